// Round 10
// baseline (157.450 us; speedup 1.0000x reference)
//
#include <hip/hip_runtime.h>
#include <math.h>

#define N      8192
#define IN_F   256
#define OUT_F  64
#define ALPHA  0.2f
#define LN_EPS 1e-5f
#define CQ     2048           // columns per wave (quarter of N)
#define CSTEP  256            // columns per step
#define NSTEP  (CQ / CSTEP)   // 8 steps

typedef __attribute__((ext_vector_type(8))) short bf16x8;
typedef __attribute__((ext_vector_type(4))) short s16x4;
typedef __attribute__((ext_vector_type(4))) float f32x4;
typedef __attribute__((ext_vector_type(4))) int   i32x4;

__device__ __forceinline__ float wave_sum(float v) {
#pragma unroll
    for (int off = 32; off >= 1; off >>= 1) v += __shfl_xor(v, off, 64);
    return v;
}

__device__ __forceinline__ short f2bf(float x) {           // RNE float->bf16
    union { float f; unsigned u; } v; v.f = x;
    unsigned r = v.u + 0x7FFF + ((v.u >> 16) & 1);
    return (short)(r >> 16);
}
__device__ __forceinline__ float bf2f(short b) {
    union { unsigned u; float f; } v; v.u = ((unsigned)(unsigned short)b) << 16;
    return v.f;
}

// ---------- Phase A: h = X@W ; store hB[j>>3][feat][j&7] bf16; f = h@a1, g = h@a2 ----------
__global__ __launch_bounds__(256) void gat_phaseA(
    const float* __restrict__ input, const float* __restrict__ W,
    const float* __restrict__ a1, const float* __restrict__ a2,
    unsigned short* __restrict__ hB, float* __restrict__ fv, float* __restrict__ gv)
{
    const int lane = threadIdx.x & 63;
    const int wid  = threadIdx.x >> 6;
    const int blockRow0 = blockIdx.x * 32;
    const int i0 = blockRow0 + wid * 8;

    float hacc[8];
#pragma unroll
    for (int r = 0; r < 8; r++) hacc[r] = 0.f;

    for (int k = 0; k < IN_F; k += 4) {
        const float w0 = W[(k + 0) * OUT_F + lane];
        const float w1 = W[(k + 1) * OUT_F + lane];
        const float w2 = W[(k + 2) * OUT_F + lane];
        const float w3 = W[(k + 3) * OUT_F + lane];
#pragma unroll
        for (int r = 0; r < 8; r++) {
            const float4 iv = *(const float4*)&input[(size_t)(i0 + r) * IN_F + k];
            hacc[r] = fmaf(iv.x, w0, hacc[r]);
            hacc[r] = fmaf(iv.y, w1, hacc[r]);
            hacc[r] = fmaf(iv.z, w2, hacc[r]);
            hacc[r] = fmaf(iv.w, w3, hacc[r]);
        }
    }

    const float a1v = a1[lane];
    const float a2v = a2[lane];

    __shared__ float hsm[32][65];
#pragma unroll
    for (int r = 0; r < 8; r++) {
        hsm[wid * 8 + r][lane] = hacc[r];
        const float fr = wave_sum(hacc[r] * a1v);
        const float gr = wave_sum(hacc[r] * a2v);
        if (lane == 0) { fv[i0 + r] = fr; gv[i0 + r] = gr; }
    }
    __syncthreads();

    const int f  = threadIdx.x >> 2;           // 0..63 feature
    const int cp = threadIdx.x & 3;            // j8 sub-block
    union { unsigned short s[8]; int4 v; } pk;
#pragma unroll
    for (int c = 0; c < 8; c++) pk.s[c] = (unsigned short)f2bf(hsm[cp * 8 + c][f]);
    *(int4*)&hB[(size_t)((blockRow0 >> 3) + cp) * 512 + f * 8] = pk.v;
}

// ---------- Main: barrier-free per-wave attention + LN + ELU ----------
// Each wave: all 16 rows x a 2048-col quarter. adj coalesced b128/row, in-wave
// LDS transpose (lgkmcnt order only, NO s_barrier in the loop), 4 feature-block
// MFMAs per k-subtile. One __syncthreads at the end to combine quarters.
__global__ __launch_bounds__(256) void gat_attn(
    const int* __restrict__ adj, const unsigned short* __restrict__ hB,
    const float* __restrict__ fv, const float* __restrict__ gv,
    const float* __restrict__ gamma, const float* __restrict__ beta,
    float* __restrict__ out)
{
    __shared__ short wtile[4][16][264];   // per-wave weight tile (pad 8 shorts)
    __shared__ float lnacc[4][16][68];    // per-wave output partials
    __shared__ float dpls[4][16];         // per-wave den partials

    const int tid  = threadIdx.x;
    const int lane = tid & 63;
    const int wid  = tid >> 6;
    const int n16  = lane & 15;
    const int g4   = lane >> 4;
    const int rowBase = blockIdx.x * 16;
    const int cbase   = wid * CQ;

    float frow[16];
#pragma unroll
    for (int q = 0; q < 4; ++q) {
        const float4 fq = *(const float4*)&fv[rowBase + q * 4];
        frow[q * 4 + 0] = fq.x; frow[q * 4 + 1] = fq.y;
        frow[q * 4 + 2] = fq.z; frow[q * 4 + 3] = fq.w;
    }

    f32x4 acc[4];
#pragma unroll
    for (int fb = 0; fb < 4; ++fb) acc[fb] = (f32x4){0.f, 0.f, 0.f, 0.f};
    float dp[16];
#pragma unroll
    for (int r = 0; r < 16; ++r) dp[r] = 0.f;

    for (int st = 0; st < NSTEP; ++st) {
        const int c0 = cbase + st * CSTEP;
        const float4 g4v = *(const float4*)&gv[c0 + lane * 4];

        // ---- weight gen: lane owns cols c0+lane*4..+3, all 16 rows ----
#pragma unroll
        for (int r = 0; r < 16; ++r) {
            const i32x4 av = *(const i32x4*)(adj + (size_t)(rowBase + r) * N + c0 + lane * 4);
            s16x4 pk;
#pragma unroll
            for (int e = 0; e < 4; ++e) {
                float t = frow[r] + ((const float*)&g4v)[e];
                t = fmaxf(t, ALPHA * t);                 // leaky_relu
                const float w = (av[e] > 0) ? __expf(t) : 0.0f;
                const short wb = f2bf(w);
                dp[r] += bf2f(wb);
                pk[e] = wb;
            }
            *(s16x4*)&wtile[wid][r][lane * 4] = pk;      // in-wave, ordered by lgkmcnt
        }

        // ---- MFMA: 8 k-subtiles x 4 feature blocks ----
#pragma unroll
        for (int ks = 0; ks < 8; ++ks) {
            const bf16x8 a = *(const bf16x8*)&wtile[wid][n16][ks * 32 + g4 * 8];
            const unsigned short* hb =
                hB + ((size_t)(c0 + ks * 32 + g4 * 8) >> 3) * 512 + n16 * 8;
#pragma unroll
            for (int fb = 0; fb < 4; ++fb) {
                const bf16x8 b = *(const bf16x8*)(hb + fb * 128);
                acc[fb] = __builtin_amdgcn_mfma_f32_16x16x32_bf16(a, b, acc[fb], 0, 0, 0);
            }
        }
    }

    // ---- per-wave den reduction ----
#pragma unroll
    for (int r = 0; r < 16; ++r) {
        const float dr = wave_sum(dp[r]);
        if (lane == 0) dpls[wid][r] = dr;
    }

    // ---- per-wave numerator partials: D[row=(g4)*4+i][feat=fb*16+n16] ----
#pragma unroll
    for (int fb = 0; fb < 4; ++fb)
#pragma unroll
        for (int i = 0; i < 4; ++i)
            lnacc[wid][g4 * 4 + i][fb * 16 + n16] = acc[fb][i];

    __syncthreads();   // the only block-wide barrier

    // ---- combine quarters + divide + LayerNorm + ELU: 16 threads per row ----
    const int r = tid >> 4;         // 0..15
    const int q = tid & 15;         // feature quad
    const float den = dpls[0][r] + dpls[1][r] + dpls[2][r] + dpls[3][r];
    const float4 v0 = *(const float4*)&lnacc[0][r][q * 4];
    const float4 v1 = *(const float4*)&lnacc[1][r][q * 4];
    const float4 v2 = *(const float4*)&lnacc[2][r][q * 4];
    const float4 v3 = *(const float4*)&lnacc[3][r][q * 4];
    const float inv = 1.0f / den;
    float vx = (v0.x + v1.x + v2.x + v3.x) * inv;
    float vy = (v0.y + v1.y + v2.y + v3.y) * inv;
    float vz = (v0.z + v1.z + v2.z + v3.z) * inv;
    float vw = (v0.w + v1.w + v2.w + v3.w) * inv;

    float sm = vx + vy + vz + vw;
#pragma unroll
    for (int o = 1; o < 16; o <<= 1) sm += __shfl_xor(sm, o, 64);
    const float mu = sm * (1.0f / 64.0f);

    const float dx = vx - mu, dy = vy - mu, dz = vz - mu, dw = vw - mu;
    float ss = dx * dx + dy * dy + dz * dz + dw * dw;
#pragma unroll
    for (int o = 1; o < 16; o <<= 1) ss += __shfl_xor(ss, o, 64);
    const float rs = rsqrtf(ss * (1.0f / 64.0f) + LN_EPS);

    const float4 gm = *(const float4*)&gamma[q * 4];
    const float4 bt = *(const float4*)&beta[q * 4];
    float y0 = dx * rs * gm.x + bt.x;
    float y1 = dy * rs * gm.y + bt.y;
    float y2 = dz * rs * gm.z + bt.z;
    float y3 = dw * rs * gm.w + bt.w;
    y0 = (y0 > 0.f) ? y0 : expm1f(y0);
    y1 = (y1 > 0.f) ? y1 : expm1f(y1);
    y2 = (y2 > 0.f) ? y2 : expm1f(y2);
    y3 = (y3 > 0.f) ? y3 : expm1f(y3);
    *(float4*)&out[(size_t)(rowBase + r) * OUT_F + q * 4] = make_float4(y0, y1, y2, y3);
}

extern "C" void kernel_launch(void* const* d_in, const int* in_sizes, int n_in,
                              void* d_out, int out_size, void* d_ws, size_t ws_size,
                              hipStream_t stream)
{
    const float* input = (const float*)d_in[0];
    const int*   adj   = (const int*)d_in[1];
    const float* W     = (const float*)d_in[2];
    const float* a1    = (const float*)d_in[3];
    const float* a2    = (const float*)d_in[4];
    const float* gamma = (const float*)d_in[5];
    const float* beta  = (const float*)d_in[6];
    float* out = (float*)d_out;

    // workspace: 1 MB hB + 32 KB f + 32 KB g
    unsigned short* hB = (unsigned short*)d_ws;
    float* fv = (float*)((char*)d_ws + 1048576);
    float* gv = fv + N;

    gat_phaseA<<<N / 32, 256, 0, stream>>>(input, W, a1, a2, hB, fv, gv);
    gat_attn<<<N / 16, 256, 0, stream>>>(adj, hB, fv, gv, gamma, beta, out);
}

// Round 11
// 94.069 us; speedup vs baseline: 1.6738x; 1.6738x over previous
//
#include <hip/hip_runtime.h>
#include <math.h>

#define N      8192
#define IN_F   256
#define OUT_F  64
#define ALPHA  0.2f
#define LN_EPS 1e-5f
#define KVB    256            // attention columns per chunk
#define NCH    (N / KVB)      // 32 chunks

typedef __attribute__((ext_vector_type(8))) short bf16x8;
typedef __attribute__((ext_vector_type(4))) short s16x4;
typedef __attribute__((ext_vector_type(4))) float f32x4;
typedef __attribute__((ext_vector_type(4))) int   i32x4;

// raw barrier: DS-visibility only, NO vmcnt drain (keeps DMA prefetch in flight)
#define BAR() do { asm volatile("s_waitcnt lgkmcnt(0)" ::: "memory"); \
                   __builtin_amdgcn_s_barrier(); } while (0)

// async global->LDS DMA, 16B/lane. lds base is wave-uniform (row start); HW
// writes lane l's 16B to base + l*16. global src carries the per-lane offset.
__device__ __forceinline__ void dma16(const void* gptr, void* lptr) {
    __builtin_amdgcn_global_load_lds(
        (const __attribute__((address_space(1))) unsigned*)gptr,
        (__attribute__((address_space(3))) unsigned*)lptr, 16, 0, 0);
}

__device__ __forceinline__ float wave_sum(float v) {
#pragma unroll
    for (int off = 32; off >= 1; off >>= 1) v += __shfl_xor(v, off, 64);
    return v;
}

__device__ __forceinline__ short f2bf(float x) {           // RNE float->bf16
    union { float f; unsigned u; } v; v.f = x;
    unsigned r = v.u + 0x7FFF + ((v.u >> 16) & 1);
    return (short)(r >> 16);
}
__device__ __forceinline__ float bf2f(short b) {
    union { unsigned u; float f; } v; v.u = ((unsigned)(unsigned short)b) << 16;
    return v.f;
}

// ---------- Phase A: h = X@W ; store hB[j>>3][feat][j&7] bf16; f = h@a1, g = h@a2 ----------
__global__ __launch_bounds__(256) void gat_phaseA(
    const float* __restrict__ input, const float* __restrict__ W,
    const float* __restrict__ a1, const float* __restrict__ a2,
    unsigned short* __restrict__ hB, float* __restrict__ fv, float* __restrict__ gv)
{
    const int lane = threadIdx.x & 63;
    const int wid  = threadIdx.x >> 6;
    const int blockRow0 = blockIdx.x * 32;
    const int i0 = blockRow0 + wid * 8;

    float hacc[8];
#pragma unroll
    for (int r = 0; r < 8; r++) hacc[r] = 0.f;

    for (int k = 0; k < IN_F; k += 4) {
        const float w0 = W[(k + 0) * OUT_F + lane];
        const float w1 = W[(k + 1) * OUT_F + lane];
        const float w2 = W[(k + 2) * OUT_F + lane];
        const float w3 = W[(k + 3) * OUT_F + lane];
#pragma unroll
        for (int r = 0; r < 8; r++) {
            const float4 iv = *(const float4*)&input[(size_t)(i0 + r) * IN_F + k];
            hacc[r] = fmaf(iv.x, w0, hacc[r]);
            hacc[r] = fmaf(iv.y, w1, hacc[r]);
            hacc[r] = fmaf(iv.z, w2, hacc[r]);
            hacc[r] = fmaf(iv.w, w3, hacc[r]);
        }
    }

    const float a1v = a1[lane];
    const float a2v = a2[lane];

    __shared__ float hsm[32][65];
#pragma unroll
    for (int r = 0; r < 8; r++) {
        hsm[wid * 8 + r][lane] = hacc[r];
        const float fr = wave_sum(hacc[r] * a1v);
        const float gr = wave_sum(hacc[r] * a2v);
        if (lane == 0) { fv[i0 + r] = fr; gv[i0 + r] = gr; }
    }
    __syncthreads();

    const int f  = threadIdx.x >> 2;           // 0..63 feature
    const int cp = threadIdx.x & 3;            // j8 sub-block
    union { unsigned short s[8]; int4 v; } pk;
#pragma unroll
    for (int c = 0; c < 8; c++) pk.s[c] = (unsigned short)f2bf(hsm[cp * 8 + c][f]);
    *(int4*)&hB[(size_t)((blockRow0 >> 3) + cp) * 512 + f * 8] = pk.v;
}

// ---------- Main: R8 structure + DMA-staged adj (counted vmcnt, dbuf LDS) ----------
// Producer: wave w owns rows w*4..+3; adj arrives via global_load_lds into the
// wave's own adjtile rows (per-wave consistency -> per-wave vmcnt suffices).
// Consumer: wave w owns feature block w. grid = 512.
__global__ __launch_bounds__(256) void gat_attn(
    const int* __restrict__ adj, const unsigned short* __restrict__ hB,
    const float* __restrict__ fv, const float* __restrict__ gv,
    const float* __restrict__ gamma, const float* __restrict__ beta,
    float* __restrict__ out)
{
    __shared__ int   adjtile[2][16][256]; // DMA-staged adj chunk, dbuf, 32 KB
    __shared__ short wls[16][264];        // weight tile, row-major, pad 8 shorts
    __shared__ float lnbuf[16][68];
    __shared__ float denbuf[16];

    const int tid  = threadIdx.x;
    const int lane = tid & 63;
    const int wid  = tid >> 6;
    const int n16  = lane & 15;
    const int g4   = lane >> 4;
    const int rowBase = blockIdx.x * 16;
    const int rbase   = rowBase + wid * 4;    // producer rows of this wave

    float frow[4];
#pragma unroll
    for (int rr = 0; rr < 4; ++rr) frow[rr] = fv[rbase + rr];

    f32x4 acc = {0.f, 0.f, 0.f, 0.f};
    float dp[4] = {0.f, 0.f, 0.f, 0.f};

    float4 gA, gB;

// stage chunk GC's 4 rows of this wave into adjtile[BUF] (async DMA)
#define STAGE(BUF, GC) do {                                                    \
    const size_t jp = (size_t)(GC) * KVB;                                      \
    _Pragma("unroll")                                                          \
    for (int rr = 0; rr < 4; ++rr)                                             \
        dma16(adj + (size_t)(rbase + rr) * N + jp + lane * 4,                  \
              &adjtile[BUF][wid * 4 + rr][0]);                                 \
} while (0)

#define STEP(C, GCUR, GNXT) do {                                               \
    /* 1: B fragments for chunk C -> regs */                                   \
    bf16x8 breg[8];                                                            \
    {                                                                          \
        const unsigned short* hb = hB + (size_t)((C) * 32 + g4) * 512          \
                                   + wid * 128 + n16 * 8;                      \
        _Pragma("unroll")                                                      \
        for (int ks = 0; ks < 8; ++ks)                                         \
            breg[ks] = *(const bf16x8*)(hb + (size_t)ks * 2048);               \
    }                                                                          \
    /* 2: stage next chunk (DMA) + g prefetch */                               \
    const int pc = ((C) + 1 < NCH) ? (C) + 1 : (C);                            \
    STAGE(((C) + 1) & 1, pc);                                                  \
    GNXT = *(const float4*)(gv + (size_t)pc * KVB + lane * 4);                 \
    /* 3: current stage retired; breg(8)+stage(4)+g(1) may stay in flight */   \
    asm volatile("s_waitcnt vmcnt(13)" ::: "memory");                          \
    __builtin_amdgcn_sched_barrier(0);                                         \
    BAR();            /* previous chunk's wls readers done (no vm drain) */    \
    /* 4: weight-gen from LDS-staged adj */                                    \
    _Pragma("unroll")                                                          \
    for (int rr = 0; rr < 4; ++rr) {                                           \
        const i32x4 av = *(const i32x4*)&adjtile[(C) & 1][wid * 4 + rr][lane * 4]; \
        s16x4 pk;                                                              \
        _Pragma("unroll")                                                      \
        for (int e = 0; e < 4; ++e) {                                          \
            float t = frow[rr] + ((const float*)&GCUR)[e];                     \
            t = fmaxf(t, ALPHA * t);               /* leaky_relu */            \
            const float w = (av[e] > 0) ? __expf(t) : 0.0f;                    \
            const short wb = f2bf(w);                                          \
            dp[rr] += bf2f(wb);                                                \
            pk[e] = wb;                                                        \
        }                                                                      \
        *(s16x4*)&wls[wid * 4 + rr][lane * 4] = pk;                            \
    }                                                                          \
    BAR();            /* wls visible (no vm drain) */                          \
    /* 5: MFMA (breg wait is counted by compiler; DMA stays in flight) */      \
    _Pragma("unroll")                                                          \
    for (int ks = 0; ks < 8; ++ks) {                                           \
        bf16x8 a = *(const bf16x8*)&wls[n16][ks * 32 + g4 * 8];                \
        acc = __builtin_amdgcn_mfma_f32_16x16x32_bf16(a, breg[ks], acc, 0, 0, 0); \
    }                                                                          \
} while (0)

    // prologue: stage chunk 0 + g(0)
    STAGE(0, 0);
    gA = *(const float4*)(gv + lane * 4);

    for (int c = 0; c < NCH; c += 2) {
        STEP(c,     gA, gB);
        STEP(c + 1, gB, gA);
    }
#undef STEP
#undef STAGE

    // ---- denominator: full-wave reduce per row slot ----
#pragma unroll
    for (int rr = 0; rr < 4; ++rr) {
        const float dr = wave_sum(dp[rr]);
        if (lane == 0) denbuf[wid * 4 + rr] = dr;
    }

    // ---- numerator: D frag -> lnbuf[row][feat] ----
#pragma unroll
    for (int r = 0; r < 4; ++r) lnbuf[g4 * 4 + r][wid * 16 + n16] = acc[r];
    __syncthreads();

    // ---- divide + LayerNorm + ELU: 16 threads per row ----
    const int r = tid >> 4;         // 0..15
    const int q = tid & 15;         // feature quad
    const float den = denbuf[r];
    float4 v = *(const float4*)&lnbuf[r][q * 4];
    const float inv = 1.0f / den;
    v.x *= inv; v.y *= inv; v.z *= inv; v.w *= inv;

    float sm = v.x + v.y + v.z + v.w;
#pragma unroll
    for (int o = 1; o < 16; o <<= 1) sm += __shfl_xor(sm, o, 64);
    const float mu = sm * (1.0f / 64.0f);

    const float dx = v.x - mu, dy = v.y - mu, dz = v.z - mu, dw = v.w - mu;
    float ss = dx * dx + dy * dy + dz * dz + dw * dw;
#pragma unroll
    for (int o = 1; o < 16; o <<= 1) ss += __shfl_xor(ss, o, 64);
    const float rs = rsqrtf(ss * (1.0f / 64.0f) + LN_EPS);

    const float4 gm = *(const float4*)&gamma[q * 4];
    const float4 bt = *(const float4*)&beta[q * 4];
    float y0 = dx * rs * gm.x + bt.x;
    float y1 = dy * rs * gm.y + bt.y;
    float y2 = dz * rs * gm.z + bt.z;
    float y3 = dw * rs * gm.w + bt.w;
    y0 = (y0 > 0.f) ? y0 : expm1f(y0);
    y1 = (y1 > 0.f) ? y1 : expm1f(y1);
    y2 = (y2 > 0.f) ? y2 : expm1f(y2);
    y3 = (y3 > 0.f) ? y3 : expm1f(y3);
    *(float4*)&out[(size_t)(rowBase + r) * OUT_F + q * 4] = make_float4(y0, y1, y2, y3);
}

extern "C" void kernel_launch(void* const* d_in, const int* in_sizes, int n_in,
                              void* d_out, int out_size, void* d_ws, size_t ws_size,
                              hipStream_t stream)
{
    const float* input = (const float*)d_in[0];
    const int*   adj   = (const int*)d_in[1];
    const float* W     = (const float*)d_in[2];
    const float* a1    = (const float*)d_in[3];
    const float* a2    = (const float*)d_in[4];
    const float* gamma = (const float*)d_in[5];
    const float* beta  = (const float*)d_in[6];
    float* out = (float*)d_out;

    // workspace: 1 MB hB + 32 KB f + 32 KB g
    unsigned short* hB = (unsigned short*)d_ws;
    float* fv = (float*)((char*)d_ws + 1048576);
    float* gv = fv + N;

    gat_phaseA<<<N / 32, 256, 0, stream>>>(input, W, a1, a2, hB, fv, gv);
    gat_attn<<<N / 16, 256, 0, stream>>>(adj, hB, fv, gv, gamma, beta, out);
}

// Round 12
// 92.058 us; speedup vs baseline: 1.7103x; 1.0218x over previous
//
#include <hip/hip_runtime.h>
#include <math.h>

#define N      8192
#define IN_F   256
#define OUT_F  64
#define ALPHA  0.2f
#define LN_EPS 1e-5f
#define KVB    512            // attention columns per chunk (widened from 256)
#define NCH    (N / KVB)      // 16 chunks

typedef __attribute__((ext_vector_type(8))) short bf16x8;
typedef __attribute__((ext_vector_type(4))) short s16x4;
typedef __attribute__((ext_vector_type(4))) float f32x4;
typedef __attribute__((ext_vector_type(4))) int   i32x4;

// raw barrier: DS-visibility only, NO vmcnt drain (keeps prefetch in flight)
#define BAR() do { asm volatile("s_waitcnt lgkmcnt(0)" ::: "memory"); \
                   __builtin_amdgcn_s_barrier(); } while (0)

__device__ __forceinline__ float wave_sum(float v) {
#pragma unroll
    for (int off = 32; off >= 1; off >>= 1) v += __shfl_xor(v, off, 64);
    return v;
}

__device__ __forceinline__ short f2bf(float x) {           // RNE float->bf16
    union { float f; unsigned u; } v; v.f = x;
    unsigned r = v.u + 0x7FFF + ((v.u >> 16) & 1);
    return (short)(r >> 16);
}
__device__ __forceinline__ float bf2f(short b) {
    union { unsigned u; float f; } v; v.u = ((unsigned)(unsigned short)b) << 16;
    return v.f;
}

// ---------- Phase A: h = X@W ; store hB[j>>3][feat][j&7] bf16; f = h@a1, g = h@a2 ----------
__global__ __launch_bounds__(256) void gat_phaseA(
    const float* __restrict__ input, const float* __restrict__ W,
    const float* __restrict__ a1, const float* __restrict__ a2,
    unsigned short* __restrict__ hB, float* __restrict__ fv, float* __restrict__ gv)
{
    const int lane = threadIdx.x & 63;
    const int wid  = threadIdx.x >> 6;
    const int blockRow0 = blockIdx.x * 32;
    const int i0 = blockRow0 + wid * 8;

    float hacc[8];
#pragma unroll
    for (int r = 0; r < 8; r++) hacc[r] = 0.f;

    for (int k = 0; k < IN_F; k += 4) {
        const float w0 = W[(k + 0) * OUT_F + lane];
        const float w1 = W[(k + 1) * OUT_F + lane];
        const float w2 = W[(k + 2) * OUT_F + lane];
        const float w3 = W[(k + 3) * OUT_F + lane];
#pragma unroll
        for (int r = 0; r < 8; r++) {
            const float4 iv = *(const float4*)&input[(size_t)(i0 + r) * IN_F + k];
            hacc[r] = fmaf(iv.x, w0, hacc[r]);
            hacc[r] = fmaf(iv.y, w1, hacc[r]);
            hacc[r] = fmaf(iv.z, w2, hacc[r]);
            hacc[r] = fmaf(iv.w, w3, hacc[r]);
        }
    }

    const float a1v = a1[lane];
    const float a2v = a2[lane];

    __shared__ float hsm[32][65];
#pragma unroll
    for (int r = 0; r < 8; r++) {
        hsm[wid * 8 + r][lane] = hacc[r];
        const float fr = wave_sum(hacc[r] * a1v);
        const float gr = wave_sum(hacc[r] * a2v);
        if (lane == 0) { fv[i0 + r] = fr; gv[i0 + r] = gr; }
    }
    __syncthreads();

    const int f  = threadIdx.x >> 2;           // 0..63 feature
    const int cp = threadIdx.x & 3;            // j8 sub-block
    union { unsigned short s[8]; int4 v; } pk;
#pragma unroll
    for (int c = 0; c < 8; c++) pk.s[c] = (unsigned short)f2bf(hsm[cp * 8 + c][f]);
    *(int4*)&hB[(size_t)((blockRow0 >> 3) + cp) * 512 + f * 8] = pk.v;
}

// ---------- Main: R8 structure, KVB=512 (16 steps, half the barriers) ----------
// Producer: wave w owns rows w*4..+3 (lane = column, coalesced adj, 2 half-chunks).
// Consumer: wave w owns feature block w. grid = 512.
__global__ __launch_bounds__(256) void gat_attn(
    const int* __restrict__ adj, const unsigned short* __restrict__ hB,
    const float* __restrict__ fv, const float* __restrict__ gv,
    const float* __restrict__ gamma, const float* __restrict__ beta,
    float* __restrict__ out)
{
    __shared__ short wls[16][520];        // weight tile 16x512, pad 8 (2-way banks, free)
    __shared__ float lnbuf[16][68];
    __shared__ float denbuf[16];

    const int tid  = threadIdx.x;
    const int lane = tid & 63;
    const int wid  = tid >> 6;
    const int n16  = lane & 15;
    const int g4   = lane >> 4;
    const int rowBase = blockIdx.x * 16;
    const int rbase   = rowBase + wid * 4;    // producer rows of this wave

    float frow[4];
#pragma unroll
    for (int rr = 0; rr < 4; ++rr) frow[rr] = fv[rbase + rr];

    f32x4 acc = {0.f, 0.f, 0.f, 0.f};
    float dp[4] = {0.f, 0.f, 0.f, 0.f};

    i32x4  adjA[8], adjB[8];                  // 4 rows x 2 half-chunks
    float4 gA[2],   gB[2];

#define PREFETCH(GC, ADJ, G) do {                                              \
    const size_t jp = (size_t)(GC) * KVB;                                      \
    _Pragma("unroll")                                                          \
    for (int rr = 0; rr < 4; ++rr)                                             \
        _Pragma("unroll")                                                      \
        for (int h = 0; h < 2; ++h)                                            \
            ADJ[rr * 2 + h] = *(const i32x4*)(adj + (size_t)(rbase + rr) * N   \
                                              + jp + h * 256 + lane * 4);      \
    G[0] = *(const float4*)(gv + jp + lane * 4);                               \
    G[1] = *(const float4*)(gv + jp + 256 + lane * 4);                         \
} while (0)

#define STEP(C, ADJ, G, NADJ, NG) do {                                         \
    /* B fragments for chunk C -> regs (issued BEFORE next adj prefetch) */    \
    bf16x8 breg[16];                                                           \
    {                                                                          \
        const unsigned short* hb = hB + (size_t)((C) * 64 + g4) * 512          \
                                   + wid * 128 + n16 * 8;                      \
        _Pragma("unroll")                                                      \
        for (int ks = 0; ks < 16; ++ks)                                        \
            breg[ks] = *(const bf16x8*)(hb + (size_t)ks * 2048);               \
    }                                                                          \
    const int pc = ((C) + 1 < NCH) ? (C) + 1 : (C);                            \
    PREFETCH(pc, NADJ, NG);                                                    \
    BAR();            /* previous chunk's wls readers done (no vm drain) */    \
    _Pragma("unroll")                                                          \
    for (int rr = 0; rr < 4; ++rr) {                                           \
        _Pragma("unroll")                                                      \
        for (int h = 0; h < 2; ++h) {                                          \
            s16x4 pk;                                                          \
            _Pragma("unroll")                                                  \
            for (int e = 0; e < 4; ++e) {                                      \
                float t = frow[rr] + ((const float*)&G[h])[e];                 \
                t = fmaxf(t, ALPHA * t);           /* leaky_relu */            \
                const float w = (((const int*)&ADJ[rr * 2 + h])[e] > 0)        \
                                ? __expf(t) : 0.0f;                            \
                const short wb = f2bf(w);                                      \
                dp[rr] += bf2f(wb);                                            \
                pk[e] = wb;                                                    \
            }                                                                  \
            *(s16x4*)&wls[wid * 4 + rr][h * 256 + lane * 4] = pk;              \
        }                                                                      \
    }                                                                          \
    BAR();            /* wls visible (no vm drain) */                          \
    _Pragma("unroll")                                                          \
    for (int ks = 0; ks < 16; ++ks) {                                          \
        bf16x8 a = *(const bf16x8*)&wls[n16][ks * 32 + g4 * 8];                \
        acc = __builtin_amdgcn_mfma_f32_16x16x32_bf16(a, breg[ks], acc, 0, 0, 0); \
    }                                                                          \
} while (0)

    PREFETCH(0, adjA, gA);
    for (int c = 0; c < NCH; c += 2) {
        STEP(c,     adjA, gA, adjB, gB);
        STEP(c + 1, adjB, gB, adjA, gA);
    }
#undef STEP
#undef PREFETCH

    // ---- denominator: full-wave reduce per row slot ----
#pragma unroll
    for (int rr = 0; rr < 4; ++rr) {
        const float dr = wave_sum(dp[rr]);
        if (lane == 0) denbuf[wid * 4 + rr] = dr;
    }

    // ---- numerator: D frag -> lnbuf[row][feat] ----
#pragma unroll
    for (int r = 0; r < 4; ++r) lnbuf[g4 * 4 + r][wid * 16 + n16] = acc[r];
    __syncthreads();

    // ---- divide + LayerNorm + ELU: 16 threads per row ----
    const int r = tid >> 4;         // 0..15
    const int q = tid & 15;         // feature quad
    const float den = denbuf[r];
    float4 v = *(const float4*)&lnbuf[r][q * 4];
    const float inv = 1.0f / den;
    v.x *= inv; v.y *= inv; v.z *= inv; v.w *= inv;

    float sm = v.x + v.y + v.z + v.w;
#pragma unroll
    for (int o = 1; o < 16; o <<= 1) sm += __shfl_xor(sm, o, 64);
    const float mu = sm * (1.0f / 64.0f);

    const float dx = v.x - mu, dy = v.y - mu, dz = v.z - mu, dw = v.w - mu;
    float ss = dx * dx + dy * dy + dz * dz + dw * dw;
#pragma unroll
    for (int o = 1; o < 16; o <<= 1) ss += __shfl_xor(ss, o, 64);
    const float rs = rsqrtf(ss * (1.0f / 64.0f) + LN_EPS);

    const float4 gm = *(const float4*)&gamma[q * 4];
    const float4 bt = *(const float4*)&beta[q * 4];
    float y0 = dx * rs * gm.x + bt.x;
    float y1 = dy * rs * gm.y + bt.y;
    float y2 = dz * rs * gm.z + bt.z;
    float y3 = dw * rs * gm.w + bt.w;
    y0 = (y0 > 0.f) ? y0 : expm1f(y0);
    y1 = (y1 > 0.f) ? y1 : expm1f(y1);
    y2 = (y2 > 0.f) ? y2 : expm1f(y2);
    y3 = (y3 > 0.f) ? y3 : expm1f(y3);
    *(float4*)&out[(size_t)(rowBase + r) * OUT_F + q * 4] = make_float4(y0, y1, y2, y3);
}

extern "C" void kernel_launch(void* const* d_in, const int* in_sizes, int n_in,
                              void* d_out, int out_size, void* d_ws, size_t ws_size,
                              hipStream_t stream)
{
    const float* input = (const float*)d_in[0];
    const int*   adj   = (const int*)d_in[1];
    const float* W     = (const float*)d_in[2];
    const float* a1    = (const float*)d_in[3];
    const float* a2    = (const float*)d_in[4];
    const float* gamma = (const float*)d_in[5];
    const float* beta  = (const float*)d_in[6];
    float* out = (float*)d_out;

    // workspace: 1 MB hB + 32 KB f + 32 KB g
    unsigned short* hB = (unsigned short*)d_ws;
    float* fv = (float*)((char*)d_ws + 1048576);
    float* gv = fv + N;

    gat_phaseA<<<N / 32, 256, 0, stream>>>(input, W, a1, a2, hB, fv, gv);
    gat_attn<<<N / 16, 256, 0, stream>>>(adj, hB, fv, gv, gamma, beta, out);
}